// Round 10
// baseline (43.112 us; speedup 1.0000x reference)
//
#include <hip/hip_runtime.h>

#define NK 512
#define NC 256
#define NH 200
#define NW 200
#define PLANE (NH * NW)
#define RSCALE 0.0625f
#define GC 8                 // channels per block
#define HGC 4                // pairing (ch, ch+4) per thread
#define XSTR 33              // xdot row stride (pw-major layout, padded)
#define NT 256               // threads per block (4 waves)

// One block per (roi k, 8-channel group), 256 threads, XCD-pinned mapping
// (xcd = blk&7 matches dispatch round-robin; cg = local*8 + xcd).
// Phase A processes a ROW PAIR x channel pair per task: 4 float4 loads,
// 16 FMAs per decode/table-read/address-chain (2x amortization vs R8/R9).
// s_xdot layout [ch][pw*33 + rel]: task's two rows adjacent (fused LDS
// writes); 33-stride spreads phase-B banks (33 % 32 = 1 -> bank ~ pw + yr).
__global__ __launch_bounds__(NT) void roi_align_maxpool(
    const float* __restrict__ feat,   // (B, C, H, W) f32
    const float* __restrict__ rois,   // (K, 5)
    float* __restrict__ out)          // (K, C, 5, 5)
{
    __shared__ float s_xdot[GC][11 * XSTR];  // 11616 B
    __shared__ float s_pool[GC][121];        // 3872 B
    __shared__ int   s_xb[11];           // absolute base col of 4-col window
    __shared__ float s_W [11][4];        // combined x-weights (validity folded)
    __shared__ int   s_yrel[11][4];      // row - ymin (plain offsets)
    __shared__ float s_wy[11][4];        // 0.25 * vy * (hy|ly)
    __shared__ int   s_meta[3];          // {ymin, nrows, b}

    const int blk = blockIdx.x;
    const int xcd = blk & 7;             // dispatch: blk % 8 -> XCD id
    const int j   = blk >> 3;
    const int k   = j & (NK - 1);        // roi, fast within an XCD's stream
    const int cg  = ((j >> 9) << 3) | xcd;   // channel-group pinned to this XCD
    const int t   = threadIdx.x;

    if (t < 22) {
        const float rx1 = rois[k * 5 + 1] * RSCALE;
        const float ry1 = rois[k * 5 + 2] * RSCALE;
        const float rx2 = rois[k * 5 + 3] * RSCALE;
        const float ry2 = rois[k * 5 + 4] * RSCALE;
        const float bin_w = fmaxf(rx2 - rx1, 1.0f) / 11.0f;
        const float bin_h = fmaxf(ry2 - ry1, 1.0f) / 11.0f;

        const int d = t / 11;            // 0 = x, 1 = y
        const int pbin = t % 11;
        const float start = d ? ry1 : rx1;
        const float bs    = d ? bin_h : bin_w;
        const int   lim   = d ? NH : NW;
        const float p = (float)pbin;
        // sub-sample coords, same expression order as reference
        float cv0 = start + (p + 0.25f) * bs;   // (0+0.5)/2
        float cv1 = start + (p + 0.75f) * bs;   // (1+0.5)/2
        const float va0 = (cv0 > -1.0f && cv0 < (float)lim) ? 1.0f : 0.0f;
        const float va1 = (cv1 > -1.0f && cv1 < (float)lim) ? 1.0f : 0.0f;
        cv0 = fminf(fmaxf(cv0, 0.0f), (float)(lim - 1));
        cv1 = fminf(fmaxf(cv1, 0.0f), (float)(lim - 1));
        const int lo0 = (int)floorf(cv0);
        const int lo1 = (int)floorf(cv1);
        const int hi0 = min(lo0 + 1, lim - 1);
        const int hi1 = min(lo1 + 1, lim - 1);
        const float fr0 = cv0 - (float)lo0;
        const float fr1 = cv1 - (float)lo1;
        if (d == 0) {
            const int xb = min(lo0, NW - 4);    // 4-col window base (lo1<=lo0+2)
            s_xb[pbin] = xb;
            s_W[pbin][0] = 0.0f; s_W[pbin][1] = 0.0f;
            s_W[pbin][2] = 0.0f; s_W[pbin][3] = 0.0f;
            s_W[pbin][lo0 - xb] += va0 * (1.0f - fr0);
            s_W[pbin][hi0 - xb] += va0 * fr0;
            s_W[pbin][lo1 - xb] += va1 * (1.0f - fr1);
            s_W[pbin][hi1 - xb] += va1 * fr1;
            if (pbin == 0) {
                // y-extent: rows monotone in (ph,sub); min row = lo(0,0),
                // max row = hi(10,1). Same expr order as y-table threads.
                float cy0 = ry1 + (0.0f + 0.25f) * bin_h;
                cy0 = fminf(fmaxf(cy0, 0.0f), (float)(NH - 1));
                const int ymin = (int)floorf(cy0);
                float cyL = ry1 + (10.0f + 0.75f) * bin_h;
                cyL = fminf(fmaxf(cyL, 0.0f), (float)(NH - 1));
                const int ymax = min((int)floorf(cyL) + 1, NH - 1);
                s_meta[0] = ymin;
                s_meta[1] = ymax - ymin + 1;    // nrows in 2..32
                s_meta[2] = (int)rois[k * 5 + 0];
            }
        } else {
            // ymin recomputed identically (avoids cross-thread ordering)
            float cy0 = ry1 + (0.0f + 0.25f) * bin_h;
            cy0 = fminf(fmaxf(cy0, 0.0f), (float)(NH - 1));
            const int ymin = (int)floorf(cy0);
            s_yrel[pbin][0] = lo0 - ymin;
            s_yrel[pbin][1] = hi0 - ymin;
            s_yrel[pbin][2] = lo1 - ymin;
            s_yrel[pbin][3] = hi1 - ymin;
            s_wy[pbin][0] = 0.25f * va0 * (1.0f - fr0);
            s_wy[pbin][1] = 0.25f * va0 * fr0;
            s_wy[pbin][2] = 0.25f * va1 * (1.0f - fr1);
            s_wy[pbin][3] = 0.25f * va1 * fr1;
        }
    }
    __syncthreads();

    // Phase A: row-pair tasks. q = rp*44 + ch4*11 + pw, rp covers rows
    // (2rp, 2rp+1). 4 float4 loads + 16 FMA per decode/table/addr chain.
    {
        const int ymin  = s_meta[0];
        const int nrows = s_meta[1];
        const int b     = s_meta[2];
        const int nrp   = (nrows + 1) >> 1;
        const int ntask = nrp * (HGC * 11);
        const float* fbase = feat + (size_t)(b * NC + cg * GC) * PLANE;
        for (int q = t; q < ntask; q += NT) {
            const int rp  = q / 44;
            const int i44 = q - rp * 44;
            const int ch4 = i44 / 11;
            const int pw  = i44 - ch4 * 11;
            const int rel0 = rp * 2;
            const bool r1 = (rel0 + 1) < nrows;
            const int    xb = s_xb[pw];
            const float4 W  = *(const float4*)s_W[pw];
            const float* fp = fbase + (size_t)ch4 * PLANE + (ymin + rel0) * NW + xb;
            const float4 v00 = *(const float4*)fp;                    // ch4,   row0
            const float4 v10 = *(const float4*)(fp + 4 * PLANE);      // ch4+4, row0
            float4 v01, v11;
            if (r1) {
                v01 = *(const float4*)(fp + NW);                      // ch4,   row1
                v11 = *(const float4*)(fp + 4 * PLANE + NW);          // ch4+4, row1
            }
            float d00 = v00.x * W.x; d00 = fmaf(v00.y, W.y, d00); d00 = fmaf(v00.z, W.z, d00); d00 = fmaf(v00.w, W.w, d00);
            float d10 = v10.x * W.x; d10 = fmaf(v10.y, W.y, d10); d10 = fmaf(v10.z, W.z, d10); d10 = fmaf(v10.w, W.w, d10);
            float* o0 = &s_xdot[ch4    ][pw * XSTR + rel0];
            float* o1 = &s_xdot[ch4 + 4][pw * XSTR + rel0];
            o0[0] = d00;
            o1[0] = d10;
            if (r1) {
                float d01 = v01.x * W.x; d01 = fmaf(v01.y, W.y, d01); d01 = fmaf(v01.z, W.z, d01); d01 = fmaf(v01.w, W.w, d01);
                float d11 = v11.x * W.x; d11 = fmaf(v11.y, W.y, d11); d11 = fmaf(v11.z, W.z, d11); d11 = fmaf(v11.w, W.w, d11);
                o0[1] = d01;
                o1[1] = d11;
            }
        }
    }
    __syncthreads();

    // Phase B: pooled bin = sum_r wy[r] * xdot[pw][row_r]  (pairing ch, ch+4)
    for (int q = t; q < HGC * 121; q += NT) {
        const int ch4 = q / 121;
        const int bin = q - ch4 * 121;
        const int ph  = bin / 11;
        const int pw  = bin - ph * 11;
        const int4   yr = *(const int4*)s_yrel[ph];
        const float4 wy = *(const float4*)s_wy[ph];
        const float* xd0 = &s_xdot[ch4    ][pw * XSTR];
        const float* xd1 = &s_xdot[ch4 + 4][pw * XSTR];
        float b0 = wy.x * xd0[yr.x];
        b0 = fmaf(wy.y, xd0[yr.y], b0);
        b0 = fmaf(wy.z, xd0[yr.z], b0);
        b0 = fmaf(wy.w, xd0[yr.w], b0);
        float b1 = wy.x * xd1[yr.x];
        b1 = fmaf(wy.y, xd1[yr.y], b1);
        b1 = fmaf(wy.z, xd1[yr.z], b1);
        b1 = fmaf(wy.w, xd1[yr.w], b1);
        s_pool[ch4    ][bin] = b0;   // 0.25 mean folded into wy
        s_pool[ch4 + 4][bin] = b1;
    }
    __syncthreads();

    // Phase C: 3x3/stride2 max-pool, contiguous 200-float store per block
    if (t < GC * 25) {
        const int ch = t / 25;
        const int r  = t % 25;
        const int oh = r / 5, ow = r % 5;
        float m = -INFINITY;
        #pragma unroll
        for (int dy = 0; dy < 3; ++dy)
            #pragma unroll
            for (int dx = 0; dx < 3; ++dx)
                m = fmaxf(m, s_pool[ch][(2 * oh + dy) * 11 + (2 * ow + dx)]);
        out[((size_t)k * NC + cg * GC) * 25 + t] = m;
    }
}

extern "C" void kernel_launch(void* const* d_in, const int* in_sizes, int n_in,
                              void* d_out, int out_size, void* d_ws, size_t ws_size,
                              hipStream_t stream) {
    const float* feat = (const float*)d_in[0];   // (4, 256, 200, 200) f32
    const float* rois = (const float*)d_in[1];   // (512, 5) f32
    float* out = (float*)d_out;                  // (512, 256, 5, 5) f32

    const int nblocks = NK * (NC / GC);          // 16384
    roi_align_maxpool<<<nblocks, NT, 0, stream>>>(feat, rois, out);
}

// Round 11
// 39.023 us; speedup vs baseline: 1.1048x; 1.1048x over previous
//
#include <hip/hip_runtime.h>

#define NK 512
#define NC 256
#define NH 200
#define NW 200
#define PLANE (NH * NW)
#define RSCALE 0.0625f
#define NT 64                // one wave per block -> __syncthreads() is waitcnt-only

// One block = ONE WAVE = one (roi k, channel pair cp -> channels 2cp, 2cp+1).
// 65536 blocks. No cross-wave synchronization at all: single-wave workgroups
// make every __syncthreads() trivial, waves are fully independent, 32/CU
// co-resident (LDS 4.4KB/block) -> maximal latency hiding, zero barrier drain.
// XCD pinning (xcd = blk&7 matches dispatch round-robin): cp = local*8 + xcd;
// resident working set per XCD = 4 ch x 4 batches x 160KB = 2.56MB < 4MB L2.
// Phase 0: lanes 0-21 build per-bin tables (LDS, wave-coherent).
// Phase A: xdot[ch][rel*11+pw] = dot4(feat row window, W[pw]); nrows*11 tasks,
//          each loading both channels (+PLANE) -> 2 float4 loads, 8 FMA.
// Phase B: pooled bin = sum_r wy[r]*xdot[row_r][pw], both channels.
// Phase C: 50 lanes 3x3/stride2 max-pool -> contiguous 50-float store.
__global__ __launch_bounds__(NT) void roi_align_maxpool(
    const float* __restrict__ feat,   // (B, C, H, W) f32
    const float* __restrict__ rois,   // (K, 5)
    float* __restrict__ out)          // (K, C, 5, 5)
{
    __shared__ float s_xdot[2][352];     // [ch][rel*11+pw]
    __shared__ float s_pool[2][121];
    __shared__ int   s_xb[11];           // absolute base col of 4-col window
    __shared__ float s_W [11][4];        // combined x-weights (validity folded)
    __shared__ int   s_yrel[11][4];      // (row - ymin) * 11
    __shared__ float s_wy[11][4];        // 0.25 * vy * (hy|ly)

    const int blk = blockIdx.x;
    const int xcd = blk & 7;             // dispatch: blk % 8 -> XCD id
    const int j   = blk >> 3;
    const int k   = j & (NK - 1);        // roi, fast within an XCD's stream
    const int cp  = ((j >> 9) << 3) | xcd;   // channel pair pinned to this XCD
    const int t   = threadIdx.x;

    // Uniform roi params (wave-uniform scalar loads, L1/L2 broadcast)
    const float rx1 = rois[k * 5 + 1] * RSCALE;
    const float ry1 = rois[k * 5 + 2] * RSCALE;
    const float rx2 = rois[k * 5 + 3] * RSCALE;
    const float ry2 = rois[k * 5 + 4] * RSCALE;
    const int   b   = (int)rois[k * 5 + 0];
    const float bin_w = fmaxf(rx2 - rx1, 1.0f) / 11.0f;
    const float bin_h = fmaxf(ry2 - ry1, 1.0f) / 11.0f;

    // Uniform y-extent (rows monotone in (ph,sub)); expressions bitwise-match
    // the table lanes: start + (p + g)*bs with constant-folded (p+g).
    float cy0 = ry1 + 0.25f * bin_h;                   // (0 + 0.25)
    cy0 = fminf(fmaxf(cy0, 0.0f), (float)(NH - 1));
    const int ymin = (int)floorf(cy0);
    float cyL = ry1 + 10.75f * bin_h;                  // (10 + 0.75)
    cyL = fminf(fmaxf(cyL, 0.0f), (float)(NH - 1));
    const int nrows = min((int)floorf(cyL) + 1, NH - 1) - ymin + 1;  // 2..32

    if (t < 22) {
        const int d = t / 11;            // 0 = x, 1 = y
        const int pbin = t % 11;
        const float start = d ? ry1 : rx1;
        const float bs    = d ? bin_h : bin_w;
        const int   lim   = d ? NH : NW;
        const float p = (float)pbin;
        // sub-sample coords, same expression order as reference
        float cv0 = start + (p + 0.25f) * bs;   // (0+0.5)/2
        float cv1 = start + (p + 0.75f) * bs;   // (1+0.5)/2
        const float va0 = (cv0 > -1.0f && cv0 < (float)lim) ? 1.0f : 0.0f;
        const float va1 = (cv1 > -1.0f && cv1 < (float)lim) ? 1.0f : 0.0f;
        cv0 = fminf(fmaxf(cv0, 0.0f), (float)(lim - 1));
        cv1 = fminf(fmaxf(cv1, 0.0f), (float)(lim - 1));
        const int lo0 = (int)floorf(cv0);
        const int lo1 = (int)floorf(cv1);
        const int hi0 = min(lo0 + 1, lim - 1);
        const int hi1 = min(lo1 + 1, lim - 1);
        const float fr0 = cv0 - (float)lo0;
        const float fr1 = cv1 - (float)lo1;
        if (d == 0) {
            const int xb = min(lo0, NW - 4);    // 4-col window base (lo1<=lo0+2)
            s_xb[pbin] = xb;
            s_W[pbin][0] = 0.0f; s_W[pbin][1] = 0.0f;
            s_W[pbin][2] = 0.0f; s_W[pbin][3] = 0.0f;
            s_W[pbin][lo0 - xb] += va0 * (1.0f - fr0);
            s_W[pbin][hi0 - xb] += va0 * fr0;
            s_W[pbin][lo1 - xb] += va1 * (1.0f - fr1);
            s_W[pbin][hi1 - xb] += va1 * fr1;
        } else {
            s_yrel[pbin][0] = (lo0 - ymin) * 11;
            s_yrel[pbin][1] = (hi0 - ymin) * 11;
            s_yrel[pbin][2] = (lo1 - ymin) * 11;
            s_yrel[pbin][3] = (hi1 - ymin) * 11;
            s_wy[pbin][0] = 0.25f * va0 * (1.0f - fr0);
            s_wy[pbin][1] = 0.25f * va0 * fr0;
            s_wy[pbin][2] = 0.25f * va1 * (1.0f - fr1);
            s_wy[pbin][3] = 0.25f * va1 * fr1;
        }
    }
    __syncthreads();   // single-wave workgroup: waitcnt only, no barrier stall

    // Phase A: task q = rel*11 + pw (= xdot slot), both channels per task.
    {
        const float* fbase = feat + (size_t)(b * NC + cp * 2) * PLANE;
        const int ntask = nrows * 11;
        for (int q = t; q < ntask; q += NT) {
            const int rel = q / 11;
            const int pw  = q - rel * 11;
            const int    xb = s_xb[pw];
            const float4 W  = *(const float4*)s_W[pw];
            const float* p0 = fbase + (ymin + rel) * NW + xb;
            const float4 v0 = *(const float4*)p0;             // ch = 2cp
            const float4 v1 = *(const float4*)(p0 + PLANE);   // ch = 2cp+1
            float d0 = v0.x * W.x; d0 = fmaf(v0.y, W.y, d0); d0 = fmaf(v0.z, W.z, d0); d0 = fmaf(v0.w, W.w, d0);
            float d1 = v1.x * W.x; d1 = fmaf(v1.y, W.y, d1); d1 = fmaf(v1.z, W.z, d1); d1 = fmaf(v1.w, W.w, d1);
            s_xdot[0][q] = d0;
            s_xdot[1][q] = d1;
        }
    }
    __syncthreads();

    // Phase B: pooled bin = sum_r wy[r] * xdot[row_r][pw], both channels
    for (int q = t; q < 121; q += NT) {
        const int ph = q / 11;
        const int pw = q - ph * 11;
        const int4   yr = *(const int4*)s_yrel[ph];
        const float4 wy = *(const float4*)s_wy[ph];
        const float* xd0 = &s_xdot[0][pw];
        const float* xd1 = &s_xdot[1][pw];
        float b0 = wy.x * xd0[yr.x];
        b0 = fmaf(wy.y, xd0[yr.y], b0);
        b0 = fmaf(wy.z, xd0[yr.z], b0);
        b0 = fmaf(wy.w, xd0[yr.w], b0);
        float b1 = wy.x * xd1[yr.x];
        b1 = fmaf(wy.y, xd1[yr.y], b1);
        b1 = fmaf(wy.z, xd1[yr.z], b1);
        b1 = fmaf(wy.w, xd1[yr.w], b1);
        s_pool[0][q] = b0;   // 0.25 mean folded into wy
        s_pool[1][q] = b1;
    }
    __syncthreads();

    // Phase C: 3x3/stride2 max-pool, contiguous 50-float store per block
    if (t < 50) {
        const int ch = t / 25;
        const int r  = t % 25;
        const int oh = r / 5, ow = r % 5;
        float m = -INFINITY;
        #pragma unroll
        for (int dy = 0; dy < 3; ++dy)
            #pragma unroll
            for (int dx = 0; dx < 3; ++dx)
                m = fmaxf(m, s_pool[ch][(2 * oh + dy) * 11 + (2 * ow + dx)]);
        out[((size_t)k * NC + cp * 2) * 25 + t] = m;
    }
}

extern "C" void kernel_launch(void* const* d_in, const int* in_sizes, int n_in,
                              void* d_out, int out_size, void* d_ws, size_t ws_size,
                              hipStream_t stream) {
    const float* feat = (const float*)d_in[0];   // (4, 256, 200, 200) f32
    const float* rois = (const float*)d_in[1];   // (512, 5) f32
    float* out = (float*)d_out;                  // (512, 256, 5, 5) f32

    const int nblocks = NK * (NC / 2);           // 65536 single-wave blocks
    roi_align_maxpool<<<nblocks, NT, 0, stream>>>(feat, rois, out);
}